// Round 6
// baseline (107.673 us; speedup 1.0000x reference)
//
#include <hip/hip_runtime.h>
#include <math.h>

#define N_FRAMES 4
#define N_FACES  320
#define N_VERTS  162
#define IMG_H    128
#define IMG_W    128
#define NWAVES   8
#define FPW      40            // faces per wave (320/8), one ballot round
#define REC_SZ   20            // floats per compacted face record
#define HW       20            // halo region width  (16 + 2*2)
#define HH       8             // halo region height (4 + 2*2)
#define HN       (HW * HH)     // 160 halo pixels per tile

// LDS arena, phase A (prologue + main loop):
//   sv   @ 0    : 162*3 floats = 1944 (pad 1952)
//   bb   @ 1952 : SoA [wave][4][48] = 6144
//   recs @ 8096 : [wave][FPW][REC_SZ] = 25600   -> total 33696
// phase B (after barrier, aliased over phase A):
//   red  @ 0     : 512*6 floats = 12288   (interior argmax partials)
//   Pbuf @ 12288 : 160*9 floats = 5760    (per-halo-pixel per-wave P partials)
//   mask @ 18048 : 160 floats   = 640     (halo mask for erode)
#define SV_OFF   0
#define BB_OFF   1952
#define BB_LD    48
#define REC_OFF  8096
#define ARENA_SZ 33696
#define RED_OFF  0
#define PB_OFF   12288
#define MK_OFF   18048

// Record (REC_SZ floats): ax,ay,e0x,e0y, e1x,e1y,invden,origidx,
//                         z0,z1,z2,invL2_0, bx,by,e12x,e12y, cx,cy,invL2_1,invL2_2

// ---------- small math helpers (fp32, op-order matched to the JAX reference) ----------

__device__ __forceinline__ void q_to_aa(const float* q, float* aa) {
    float q1 = q[1], q2 = q[2], q3 = q[3];
    float sin_sq = (q1 * q1 + q2 * q2) + q3 * q3;
    float sin_t = sqrtf(sin_sq + 1e-20f);
    float cos_t = q[0];
    float two_theta = (cos_t < 0.0f) ? (2.0f * atan2f(-sin_t, -cos_t))
                                     : (2.0f * atan2f(sin_t, cos_t));
    float k = (sin_sq > 1e-12f) ? (two_theta / sin_t) : 2.0f;
    aa[0] = q1 * k; aa[1] = q2 * k; aa[2] = q3 * k;
}

__device__ __forceinline__ void aa_to_R(const float* aa, float* R) {
    float th = sqrtf(((aa[0] * aa[0] + aa[1] * aa[1]) + aa[2] * aa[2]) + 1e-12f);
    float kx = aa[0] / th, ky = aa[1] / th, kz = aa[2] / th;
    float K[9] = { 0.0f, -kz,  ky,
                   kz,  0.0f, -kx,
                  -ky,   kx, 0.0f };
    float s = sinf(th), c = cosf(th);
    float KK[9];
    for (int i = 0; i < 3; ++i)
        for (int j = 0; j < 3; ++j)
            KK[i*3+j] = (K[i*3+0] * K[0*3+j] + K[i*3+1] * K[1*3+j]) + K[i*3+2] * K[2*3+j];
    float omc = 1.0f - c;
    for (int i = 0; i < 9; ++i) {
        float eye = (i == 0 || i == 4 || i == 8) ? 1.0f : 0.0f;
        R[i] = (eye + s * K[i]) + omc * KK[i];
    }
}

__device__ __forceinline__ void mat3mul(const float* A, const float* B, float* C) {
    for (int i = 0; i < 3; ++i)
        for (int j = 0; j < 3; ++j)
            C[i*3+j] = (A[i*3+0] * B[0*3+j] + A[i*3+1] * B[1*3+j]) + A[i*3+2] * B[2*3+j];
}

// P-factor (1 - prob) of one face at one pixel — expression order matches reference.
__device__ __forceinline__ float face_factor(float px, float py, const float* d) {
    float ax = d[0], ay = d[1], e0x = d[2], e0y = d[3];
    float e1x = d[4], e1y = d[5], invden = d[6];
    float invL2_0 = d[11];
    float bx = d[12], by = d[13], e12x = d[14], e12y = d[15];
    float cx = d[16], cy = d[17], invL2_1 = d[18], invL2_2 = d[19];

    float dx = px - ax, dy = py - ay;
    float w1 = (dx * e1y - dy * e1x) * invden;
    float w2 = (e0x * dy - e0y * dx) * invden;
    float w0 = (1.0f - w1) - w2;
    bool inside = (w0 >= 0.0f) & (w1 >= 0.0f) & (w2 >= 0.0f);
    // edge 0: a->b
    float t0 = fminf(fmaxf((dx * e0x + dy * e0y) * invL2_0, 0.0f), 1.0f);
    float x0 = dx - t0 * e0x, y0 = dy - t0 * e0y;
    float dd = x0 * x0 + y0 * y0;
    // edge 1: b->c
    float rx1 = px - bx, ry1 = py - by;
    float t1 = fminf(fmaxf((rx1 * e12x + ry1 * e12y) * invL2_1, 0.0f), 1.0f);
    float x1 = rx1 - t1 * e12x, y1 = ry1 - t1 * e12y;
    dd = fminf(dd, x1 * x1 + y1 * y1);
    // edge 2: c->a (edge vector = -e1, exact fp negation)
    float ex2 = -e1x, ey2 = -e1y;
    float rx2 = px - cx, ry2 = py - cy;
    float t2 = fminf(fmaxf((rx2 * ex2 + ry2 * ey2) * invL2_2, 0.0f), 1.0f);
    float x2 = rx2 - t2 * ex2, y2 = ry2 - t2 * ey2;
    dd = fminf(dd, x2 * x2 + y2 * y2);
    float d2 = inside ? 0.0f : dd;
    return 1.0f - __expf(-7000.0f * d2);
}

// ---------- single fused kernel: setup + raster + mask + erode + texture ----------
// Block = 512 threads = 8 waves, one 16x4 output tile, one frame.
// Wave w owns faces [40w, 40w+40) (ballot-compacted). Cull vs the HALO rect with
// margin 0.0026 > 25*ln2/7000: skipped faces contribute a factor that rounds to
// exactly 1.0f at every halo pixel and cannot be inside -> skip is bit-exact.
// Each lane: argmax partial for its interior pixel + P partials for <=3 owned
// halo pixels. Erode = 1 - max(P) over the 5x5 window (min of mask), computed
// from the in-LDS halo mask; OOB window entries = +inf (excluded), matching
// the reference's -inf padding under max(-m).

__global__ void __launch_bounds__(512)
render_kernel(const float* __restrict__ verts_in,   // 162*3
              const float* __restrict__ transl,     // 6 floats
              const float* __restrict__ quat,       // 8 floats
              const float* __restrict__ expv,       // 1 float
              const int*   __restrict__ faces,      // 320*3
              const float* __restrict__ ffeat,      // (320,3,2)
              const float* __restrict__ tex,        // (3,256,256)
              float* __restrict__ out)              // (4,4,128,128)
{
    __shared__ __align__(16) char arena[ARENA_SZ];
    float* sv   = (float*)(arena + SV_OFF);
    float* bb   = (float*)(arena + BB_OFF);
    float* recs = (float*)(arena + REC_OFF);
    float* red  = (float*)(arena + RED_OFF);       // phase B, aliased
    float* Pbuf = (float*)(arena + PB_OFF);        // phase B, aliased
    float* mk   = (float*)(arena + MK_OFF);        // phase B, aliased

    int frame = blockIdx.x >> 8;                   // 1024 blocks: 256 tiles/frame
    int blk   = blockIdx.x & 255;
    int tid   = threadIdx.x;
    int lane  = tid & 63;
    int wv    = __builtin_amdgcn_readfirstlane(tid >> 6);
    int tile_x = blk & 7, tile_y = blk >> 3;
    int j = tile_x * 16 + (lane & 15);
    int i = tile_y * 4 + (lane >> 4);

    // ---- prologue phase 1: rotation chain (redundant per thread; uniform) ----
    float e = expv[0];
    float R[9];
    {
        float aa0[3], aa1[3], S[9];
        q_to_aa(quat, aa0);
        aa_to_R(aa0, R);
        q_to_aa(quat + 4, aa1);                    // angles (ROT_DIVIDE = 1)
        float arg[3];
        for (int t = 0; t < 3; ++t) arg[t] = (e * aa1[t]) / 4.0f;
        aa_to_R(arg, S);
        for (int t = 0; t < frame; ++t) {          // rot = rot @ rot_step, k times
            float nxt[9];
            mat3mul(R, S, nxt);
            for (int q = 0; q < 9; ++q) R[q] = nxt[q];
        }
    }

    // ---- prologue phase 2: camera-space vertices for THIS frame ----
    if (tid < N_VERTS) {
        float te = (float)((double)frame / 3.0) * e;
        float vx = verts_in[tid*3+0], vy = verts_in[tid*3+1], vz = verts_in[tid*3+2];
        float dx_ = (R[0] * vx + R[1] * vy) + R[2] * vz;
        float dy_ = (R[3] * vx + R[4] * vy) + R[5] * vz;
        float dz_ = (R[6] * vx + R[7] * vy) + R[8] * vz;
        float x = (dx_ + transl[0]) + te * transl[3];
        float y = (dy_ + transl[1]) + te * transl[4];
        float z = (dz_ + transl[2]) + te * transl[5];
        z = z - 2.0f;                              // v_cam = verts - [0,0,CAM_DIST]
        sv[tid*3+0] = x; sv[tid*3+1] = y; sv[tid*3+2] = z;
    }
    __syncthreads();

    // ---- prologue phase 3: per-wave face setup + ballot compaction ----
    const float FOCAL = (float)(1.0 / tan(1.57 / 4.0));
    int cnt;
    {
        bool valid = false;
        float ax=0, ay=0, bx=0, by=0, cx=0, cy=0, e0x=0, e0y=0, e1x=0, e1y=0;
        float e12x=0, e12y=0, z0=0, z1=0, z2=0, den=0;
        int f = wv * FPW + lane;
        if (lane < FPW) {
            int i0 = faces[f*3+0], i1 = faces[f*3+1], i2 = faces[f*3+2];
            const float* A = &sv[i0*3];
            const float* B = &sv[i1*3];
            const float* C = &sv[i2*3];
            float ux = B[0] - A[0], uy = B[1] - A[1];
            float wx = C[0] - A[0], wy = C[1] - A[1];
            float nz = ux * wy - uy * wx;          // sign of face-normal z
            float da = -A[2] + 1e-10f, db = -B[2] + 1e-10f, dc = -C[2] + 1e-10f;
            ax = (FOCAL * A[0]) / da; ay = (FOCAL * A[1]) / da;
            bx = (FOCAL * B[0]) / db; by = (FOCAL * B[1]) / db;
            cx = (FOCAL * C[0]) / dc; cy = (FOCAL * C[1]) / dc;
            e0x = bx - ax; e0y = by - ay;
            e1x = cx - ax; e1y = cy - ay;
            e12x = cx - bx; e12y = cy - by;
            den = e0x * e1y - e0y * e1x;
            z0 = A[2]; z1 = B[2]; z2 = C[2];
            valid = (fabsf(den) > 1e-10f) && (nz > 0.0f);
        }
        unsigned long long m = __ballot(valid);
        cnt = __popcll(m);
        if (valid) {
            unsigned long long lmask = (lane == 63) ? 0x7fffffffffffffffull
                                                    : ((1ull << lane) - 1ull);
            int pos = __popcll(m & lmask);
            float invden = 1.0f / den;
            float L2_0 = (e0x * e0x + e0y * e0y) + 1e-12f;
            float L2_1 = (e12x * e12x + e12y * e12y) + 1e-12f;
            float L2_2 = (e1x * e1x + e1y * e1y) + 1e-12f;  // |(-e1)|^2 == |e1|^2
            float4* r = (float4*)&recs[(wv * FPW + pos) * REC_SZ];
            r[0] = make_float4(ax, ay, e0x, e0y);
            r[1] = make_float4(e1x, e1y, invden, (float)f);
            r[2] = make_float4(z0, z1, z2, 1.0f / L2_0);
            r[3] = make_float4(bx, by, e12x, e12y);
            r[4] = make_float4(cx, cy, 1.0f / L2_1, 1.0f / L2_2);
            float* wbb = &bb[wv * 4 * BB_LD];
            wbb[0*BB_LD + pos] = fminf(fminf(ax, bx), cx);
            wbb[1*BB_LD + pos] = fminf(fminf(ay, by), cy);
            wbb[2*BB_LD + pos] = fmaxf(fmaxf(ax, bx), cx);
            wbb[3*BB_LD + pos] = fmaxf(fmaxf(ay, by), cy);
        }
    }
    // No barrier: each wave reads only its own compacted segment.

    // ---- pixel coordinates: own interior pixel + <=3 owned halo pixels ----
    float px = (float)(-1.0 + 2.0 * (double)j / 127.0);
    float py = (float)( 1.0 - 2.0 * (double)i / 127.0);

    float hpx[3], hpy[3];
    bool  hin[3];
    float Ph[3] = {1.0f, 1.0f, 1.0f};
    #pragma unroll
    for (int k = 0; k < 3; ++k) {
        int h = lane + 64 * k;
        int hy = h / HW, hx = h - hy * HW;
        int ii = tile_y * 4 - 2 + hy;
        int jj = tile_x * 16 - 2 + hx;
        hin[k] = (h < HN) && (ii >= 0) && (ii < IMG_H) && (jj >= 0) && (jj < IMG_W);
        hpx[k] = (float)(-1.0 + 2.0 * (double)jj / 127.0);
        hpy[k] = (float)( 1.0 - 2.0 * (double)ii / 127.0);
    }

    // ---- cull vs HALO rect -> relevance bitmask (wave-uniform) ----
    unsigned long long fmask;
    {
        float txmin = (float)(-1.0 + 2.0 * (double)(tile_x * 16 - 2) / 127.0);
        float txmax = (float)(-1.0 + 2.0 * (double)(tile_x * 16 + 17) / 127.0);
        float tymax = (float)( 1.0 - 2.0 * (double)(tile_y * 4 - 2) / 127.0);
        float tymin = (float)( 1.0 - 2.0 * (double)(tile_y * 4 + 5) / 127.0);
        int l = (lane < FPW) ? lane : 0;
        const float* wbb = &bb[wv * 4 * BB_LD];
        float xmin = wbb[0*BB_LD + l], ymin = wbb[1*BB_LD + l];
        float xmax = wbb[2*BB_LD + l], ymax = wbb[3*BB_LD + l];
        float cdx = fmaxf(fmaxf(xmin - txmax, txmin - xmax), 0.0f);
        float cdy = fmaxf(fmaxf(ymin - tymax, tymin - ymax), 0.0f);
        bool near = ((cdx * cdx + cdy * cdy) <= 0.0026f) && (lane < cnt);
        fmask = __ballot(near);
    }

    // ---- main loop over this wave's relevant faces ----
    float best = -1e10f;
    int bestf = 0;
    float bw0 = 0.0f, bw1 = 0.0f, bw2 = 0.0f;

    while (fmask) {
        int fc = __ffsll((unsigned long long)fmask) - 1;    // wave-uniform
        fmask &= fmask - 1;
        const float* d = &recs[(wv * FPW + fc) * REC_SZ];   // uniform -> broadcast

        // argmax partial at own interior pixel
        {
            float dx = px - d[0], dy = py - d[1];
            float w1 = (dx * d[5] - dy * d[4]) * d[6];
            float w2 = (d[2] * dy - d[3] * dx) * d[6];
            float w0 = (1.0f - w1) - w2;
            bool inside = (w0 >= 0.0f) & (w1 >= 0.0f) & (w2 >= 0.0f);
            float zi = (w0 * d[8] + w1 * d[9]) + w2 * d[10];
            float score = inside ? zi : -1e10f;
            if (score > best) {
                best = score; bestf = (int)d[7]; bw0 = w0; bw1 = w1; bw2 = w2;
            }
        }
        // P partials at owned halo pixels
        #pragma unroll
        for (int k = 0; k < 3; ++k)
            if (hin[k]) Ph[k] *= face_factor(hpx[k], hpy[k], d);
    }

    // ---- phase B: write partials (arena aliased behind barrier) ----
    __syncthreads();                               // all waves done with sv/bb/recs
    {
        float* my = &red[tid * 6];
        my[0] = best; my[1] = __int_as_float(bestf);
        my[2] = bw0;  my[3] = bw1; my[4] = bw2; my[5] = 0.0f;
        #pragma unroll
        for (int k = 0; k < 3; ++k) {
            int h = lane + 64 * k;
            if (h < HN) Pbuf[h * 9 + wv] = Ph[k];
        }
    }
    __syncthreads();

    // ---- halo mask: mask[h] = 1 - prod_w P, or +inf if out of image ----
    if (tid < HN) {
        int hy = tid / HW, hx = tid - hy * HW;
        int ii = tile_y * 4 - 2 + hy;
        int jj = tile_x * 16 - 2 + hx;
        bool inb = (ii >= 0) && (ii < IMG_H) && (jj >= 0) && (jj < IMG_W);
        if (inb) {
            float Pt = Pbuf[tid * 9 + 0];
            for (int w = 1; w < NWAVES; ++w) Pt *= Pbuf[tid * 9 + w];
            mk[tid] = 1.0f - Pt;
        } else {
            mk[tid] = 1e30f;                       // excluded from the window min
        }
    }
    __syncthreads();

    // ---- epilogue: argmax combine + texture + erode, threads 0..63 ----
    if (tid < 64) {
        float bbst = red[tid * 6 + 0];
        int   bf   = __float_as_int(red[tid * 6 + 1]);
        float r0 = red[tid * 6 + 2], r1 = red[tid * 6 + 3], r2 = red[tid * 6 + 4];
        for (int w = 1; w < NWAVES; ++w) {
            const float* s = &red[(w * 64 + tid) * 6];
            float sc = s[0]; int ff = __float_as_int(s[1]);
            if ((sc > bbst) || ((sc == bbst) && (ff < bf))) {
                bbst = sc; bf = ff; r0 = s[2]; r1 = s[3]; r2 = s[4];
            }
        }

        bool hit = bbst != -1e10f;
        float uv0 = 0.0f, uv1 = 0.0f;
        if (hit) {
            const float* fp = ffeat + bf * 6;
            uv0 = (fp[0] * r0 + fp[2] * r1) + fp[4] * r2;
            uv1 = (fp[1] * r0 + fp[3] * r1) + fp[5] * r2;
        }
        float u = fminf(fmaxf(uv0, 0.0f), 1.0f) * 255.0f;
        float v = (1.0f - fminf(fmaxf(uv1, 0.0f), 1.0f)) * 255.0f;
        float x0f = floorf(u), y0f = floorf(v);
        float fx = u - x0f, fy = v - y0f;
        int x0i = min(max((int)x0f, 0), 255);
        int x1i = min(x0i + 1, 255);
        int y0i = min(max((int)y0f, 0), 255);
        int y1i = min(y0i + 1, 255);

        for (int c = 0; c < 3; ++c) {
            const float* tc = tex + c * 65536;
            float t00 = tc[y0i * 256 + x0i];
            float t01 = tc[y0i * 256 + x1i];
            float t10 = tc[y1i * 256 + x0i];
            float t11 = tc[y1i * 256 + x1i];
            float val = (t00 * (1.0f - fx)) * (1.0f - fy);
            val = val + (t01 * fx) * (1.0f - fy);
            val = val + (t10 * (1.0f - fx)) * fy;
            val = val + (t11 * fx) * fy;
            out[((frame * 4 + c) * IMG_H + i) * IMG_W + j] = val;
        }

        // 5x5 erode from the halo mask (window rows ly..ly+4, cols lx..lx+4)
        int ly = tid >> 4, lx = tid & 15;
        float m = 1e30f;
        #pragma unroll
        for (int di = 0; di < 5; ++di)
            #pragma unroll
            for (int dj = 0; dj < 5; ++dj)
                m = fminf(m, mk[(ly + di) * HW + (lx + dj)]);
        out[((frame * 4 + 3) * IMG_H + i) * IMG_W + j] = m;
    }
}

// ---------- launcher: single dispatch ----------

extern "C" void kernel_launch(void* const* d_in, const int* in_sizes, int n_in,
                              void* d_out, int out_size, void* d_ws, size_t ws_size,
                              hipStream_t stream) {
    const float* vertices      = (const float*)d_in[0];
    const float* translation   = (const float*)d_in[1];
    const float* quaternion    = (const float*)d_in[2];
    const float* expv          = (const float*)d_in[3];
    const float* face_features = (const float*)d_in[4];
    const float* texture_maps  = (const float*)d_in[5];
    const int*   faces         = (const int*)d_in[6];
    float* out = (float*)d_out;

    render_kernel<<<N_FRAMES * 256, 512, 0, stream>>>(vertices, translation,
                                                      quaternion, expv, faces,
                                                      face_features, texture_maps,
                                                      out);
}

// Round 7
// 93.529 us; speedup vs baseline: 1.1512x; 1.1512x over previous
//
#include <hip/hip_runtime.h>
#include <math.h>

#define N_FRAMES 4
#define N_FACES  320
#define N_VERTS  162
#define IMG_H    128
#define IMG_W    128
#define REC_SZ   20            // floats per compacted face record
#define NWAVES   4             // waves per raster block (face-split factor)

// Record (REC_SZ floats): ax,ay,e0x,e0y, e1x,e1y,invden,origidx,
//                         z0,z1,z2,invL2_0, bx,by,e12x,e12y, cx,cy,invL2_1,invL2_2
// Workspace layout (floats):
//   [0..3]           faceCount (int)
//   bbg  @ 4         bbox SoA: [frame][4][320]   (xmin,ymin,xmax,ymax planes)
//   recs @ 5124      [frame][320][REC_SZ]        (byte offset 20496, 16-aligned)
//   mask @ 30724     [frame][128][128]

// ---------- small math helpers (fp32, op-order matched to the JAX reference) ----------

__device__ __forceinline__ void q_to_aa(const float* q, float* aa) {
    float q1 = q[1], q2 = q[2], q3 = q[3];
    float sin_sq = (q1 * q1 + q2 * q2) + q3 * q3;
    float sin_t = sqrtf(sin_sq + 1e-20f);
    float cos_t = q[0];
    float two_theta = (cos_t < 0.0f) ? (2.0f * atan2f(-sin_t, -cos_t))
                                     : (2.0f * atan2f(sin_t, cos_t));
    float k = (sin_sq > 1e-12f) ? (two_theta / sin_t) : 2.0f;
    aa[0] = q1 * k; aa[1] = q2 * k; aa[2] = q3 * k;
}

__device__ __forceinline__ void aa_to_R(const float* aa, float* R) {
    float th = sqrtf(((aa[0] * aa[0] + aa[1] * aa[1]) + aa[2] * aa[2]) + 1e-12f);
    float kx = aa[0] / th, ky = aa[1] / th, kz = aa[2] / th;
    float K[9] = { 0.0f, -kz,  ky,
                   kz,  0.0f, -kx,
                  -ky,   kx, 0.0f };
    float s = sinf(th), c = cosf(th);
    float KK[9];
    for (int i = 0; i < 3; ++i)
        for (int j = 0; j < 3; ++j)
            KK[i*3+j] = (K[i*3+0] * K[0*3+j] + K[i*3+1] * K[1*3+j]) + K[i*3+2] * K[2*3+j];
    float omc = 1.0f - c;
    for (int i = 0; i < 9; ++i) {
        float eye = (i == 0 || i == 4 || i == 8) ? 1.0f : 0.0f;
        R[i] = (eye + s * K[i]) + omc * KK[i];
    }
}

__device__ __forceinline__ void mat3mul(const float* A, const float* B, float* C) {
    for (int i = 0; i < 3; ++i)
        for (int j = 0; j < 3; ++j)
            C[i*3+j] = (A[i*3+0] * B[0*3+j] + A[i*3+1] * B[1*3+j]) + A[i*3+2] * B[2*3+j];
}

// ---------- kernel 1: rotation chain, vertex transform, face setup + compaction ----------

__global__ void __launch_bounds__(256)
setup_kernel(const float* __restrict__ verts_in,   // 162*3
             const float* __restrict__ transl,     // 6 floats
             const float* __restrict__ quat,       // 8 floats
             const float* __restrict__ expv,       // 1 float
             const int*   __restrict__ faces,      // 320*3
             int*   __restrict__ faceCount,        // 4 ints
             float* __restrict__ bbg,              // [4][4][320]
             float* __restrict__ recsg)            // [4][320][REC_SZ]
{
    __shared__ float rots[N_FRAMES][9];
    __shared__ float sv[N_FRAMES][N_VERTS * 3];    // camera-space verts
    int tid = threadIdx.x;

    if (tid == 0) {
        float aa0[3], aa1[3], R0[9], step[9];
        q_to_aa(quat, aa0);
        aa_to_R(aa0, R0);
        q_to_aa(quat + 4, aa1);                    // angles (ROT_DIVIDE = 1)
        float e = expv[0];
        float arg[3];
        for (int i = 0; i < 3; ++i) arg[i] = (e * aa1[i]) / 4.0f;   // exp*angles/FMO_STEPS
        aa_to_R(arg, step);
        float cur[9];
        for (int i = 0; i < 9; ++i) { cur[i] = R0[i]; rots[0][i] = R0[i]; }
        for (int k = 1; k < N_FRAMES; ++k) {
            float nxt[9];
            mat3mul(cur, step, nxt);               // rot = rot @ rot_step (sequential)
            for (int i = 0; i < 9; ++i) { cur[i] = nxt[i]; rots[k][i] = nxt[i]; }
        }
    }
    __syncthreads();

    float e = expv[0];
    float t0 = transl[0], t1 = transl[1], t2 = transl[2];   // trans_start
    float u0 = transl[3], u1 = transl[4], u2 = transl[5];   // translation term p=1

    for (int item = tid; item < N_FRAMES * N_VERTS; item += blockDim.x) {
        int k = item / N_VERTS, v = item - k * N_VERTS;
        float te = (float)((double)k / 3.0) * e;            // f32(linspace ti) * exp
        float vx = verts_in[v*3+0], vy = verts_in[v*3+1], vz = verts_in[v*3+2];
        const float* R = rots[k];
        float dx_ = (R[0] * vx + R[1] * vy) + R[2] * vz;
        float dy_ = (R[3] * vx + R[4] * vy) + R[5] * vz;
        float dz_ = (R[6] * vx + R[7] * vy) + R[8] * vz;
        float x = (dx_ + t0) + te * u0;
        float y = (dy_ + t1) + te * u1;
        float z = (dz_ + t2) + te * u2;
        z = z - 2.0f;                                       // v_cam = verts - [0,0,CAM_DIST]
        sv[k][v*3+0] = x; sv[k][v*3+1] = y; sv[k][v*3+2] = z;
    }
    __syncthreads();

    const float FOCAL = (float)(1.0 / tan(1.57 / 4.0));

    // One wave per frame; stable (order-preserving) compaction of valid faces.
    int w    = tid >> 6;                                    // frame
    int lane = tid & 63;
    unsigned long long lmask = (lane == 63) ? 0x7fffffffffffffffull
                                            : ((1ull << lane) - 1ull);
    int cnt = 0;
    for (int base = 0; base < N_FACES; base += 64) {        // 320 = 5*64 exact
        int f = base + lane;
        int i0 = faces[f*3+0], i1 = faces[f*3+1], i2 = faces[f*3+2];
        const float* A = &sv[w][i0*3];
        const float* B = &sv[w][i1*3];
        const float* C = &sv[w][i2*3];
        float ux = B[0] - A[0], uy = B[1] - A[1];
        float wx = C[0] - A[0], wy = C[1] - A[1];
        float nz = ux * wy - uy * wx;                       // sign of face-normal z
        float da = -A[2] + 1e-10f, db = -B[2] + 1e-10f, dc = -C[2] + 1e-10f;
        float ax = (FOCAL * A[0]) / da, ay = (FOCAL * A[1]) / da;
        float bx = (FOCAL * B[0]) / db, by = (FOCAL * B[1]) / db;
        float cx = (FOCAL * C[0]) / dc, cy = (FOCAL * C[1]) / dc;
        float e0x = bx - ax, e0y = by - ay;                 // a->b
        float e1x = cx - ax, e1y = cy - ay;                 // a->c
        float e12x = cx - bx, e12y = cy - by;               // b->c
        float den = e0x * e1y - e0y * e1x;
        bool dok = fabsf(den) > 1e-10f;
        bool valid = dok && (nz > 0.0f);
        unsigned long long m = __ballot(valid);
        if (valid) {
            float invden = 1.0f / den;
            float L2_0 = (e0x * e0x + e0y * e0y) + 1e-12f;
            float L2_1 = (e12x * e12x + e12y * e12y) + 1e-12f;
            float L2_2 = (e1x * e1x + e1y * e1y) + 1e-12f;  // |(-e1)|^2 == |e1|^2
            int pos = cnt + __popcll(m & lmask);
            float4* r = (float4*)&recsg[(w * N_FACES + pos) * REC_SZ];
            r[0] = make_float4(ax, ay, e0x, e0y);
            r[1] = make_float4(e1x, e1y, invden, (float)f);
            r[2] = make_float4(A[2], B[2], C[2], 1.0f / L2_0);
            r[3] = make_float4(bx, by, e12x, e12y);
            r[4] = make_float4(cx, cy, 1.0f / L2_1, 1.0f / L2_2);
            bbg[(w * 4 + 0) * N_FACES + pos] = fminf(fminf(ax, bx), cx);
            bbg[(w * 4 + 1) * N_FACES + pos] = fminf(fminf(ay, by), cy);
            bbg[(w * 4 + 2) * N_FACES + pos] = fmaxf(fmaxf(ax, bx), cx);
            bbg[(w * 4 + 3) * N_FACES + pos] = fmaxf(fmaxf(ay, by), cy);
        }
        cnt += __popcll(m);
    }
    if (lane == 0) faceCount[w] = cnt;
}

// ---------- kernel 2: raster, 8x8 tile per block, 1 pixel/lane, 4-way face split ----------
// Cull: pixel-rect vs face bbox distance^2 > 0.0026 (> 25*ln2/7000 = 0.002476)
// => prob rounds to exactly 1.0f for every tile pixel and the face cannot be
// inside -> skipping is bit-exact. Culled set split round-robin over 4 waves.

__global__ void __launch_bounds__(256)
raster_kernel(const int*   __restrict__ faceCount,
              const float* __restrict__ bbg,      // [4][4][320]
              const float* __restrict__ recsg,    // [4][320][REC_SZ]
              const float* __restrict__ ffeat,    // (320,3,2)
              const float* __restrict__ tex,      // (3,256,256)
              float* __restrict__ out,            // (4,4,128,128)
              float* __restrict__ maskbuf)        // (4,128,128)
{
    __shared__ float4 srecs[N_FACES * 5];          // whole-frame record table
    __shared__ float  sred[256 * 7];               // reduction, stride 7 (conflict-light)

    int frame = blockIdx.x >> 8;                   // 1024 blocks: 256 tiles/frame
    int t     = blockIdx.x & 255;
    int tid   = threadIdx.x;
    int lane  = tid & 63;
    int wv    = __builtin_amdgcn_readfirstlane(tid >> 6);
    int tx = t & 15, ty = t >> 4;                  // 16x16 grid of 8x8 tiles
    int j = tx * 8 + (lane & 7);
    int i = ty * 8 + (lane >> 3);

    int nv = faceCount[frame];
    int rounds = (nv + 63) >> 6;                   // <= 5

    // stage this frame's records into LDS (coalesced float4)
    {
        const float4* g = (const float4*)(recsg + frame * N_FACES * REC_SZ);
        for (int idx = tid; idx < nv * 5; idx += 256) srecs[idx] = g[idx];
    }
    __syncthreads();

    // pixel coordinates (f32 of the f64 linspace, as in the reference)
    float px = (float)(-1.0 + 2.0 * (double)j / 127.0);
    float py = (float)( 1.0 - 2.0 * (double)i / 127.0);

    // tile rectangle for the cull
    float txmin = (float)(-1.0 + 2.0 * (double)(tx * 8) / 127.0);
    float txmax = (float)(-1.0 + 2.0 * (double)(tx * 8 + 7) / 127.0);
    float tymax = (float)( 1.0 - 2.0 * (double)(ty * 8) / 127.0);
    float tymin = (float)( 1.0 - 2.0 * (double)(ty * 8 + 7) / 127.0);

    // cull: lane l tests face c*64+l -> per-round bitmasks (wave-uniform values)
    unsigned long long masks[5];
    for (int c = 0; c < rounds; ++c) {
        int f = c * 64 + lane;
        bool near = false;
        if (f < nv) {
            float xmin = bbg[(frame * 4 + 0) * N_FACES + f];
            float ymin = bbg[(frame * 4 + 1) * N_FACES + f];
            float xmax = bbg[(frame * 4 + 2) * N_FACES + f];
            float ymax = bbg[(frame * 4 + 3) * N_FACES + f];
            float cdx = fmaxf(fmaxf(xmin - txmax, txmin - xmax), 0.0f);
            float cdy = fmaxf(fmaxf(ymin - tymax, tymin - ymax), 0.0f);
            near = (cdx * cdx + cdy * cdy) <= 0.0026f;
        }
        masks[c] = __ballot(near);
    }

    // main loop: near faces, round-robin split over the 4 waves
    float best = -1e10f;
    int bestf = 0;
    float bw0 = 0.0f, bw1 = 0.0f, bw2 = 0.0f;
    float P = 1.0f;
    int sel = 0;

    for (int c = 0; c < rounds; ++c) {
        unsigned long long m = masks[c];
        while (m) {
            int b = __ffsll(m) - 1;
            m &= m - 1;
            if (((sel++) & 3) != wv) continue;     // wave-uniform skip (~5 inst)
            const float* d = (const float*)&srecs[(c * 64 + b) * 5]; // broadcast

            float ax = d[0], ay = d[1], e0x = d[2], e0y = d[3];
            float e1x = d[4], e1y = d[5], invden = d[6], fidx = d[7];
            float z0 = d[8], z1 = d[9], z2 = d[10], invL2_0 = d[11];
            float bx = d[12], by = d[13], e12x = d[14], e12y = d[15];
            float cx = d[16], cy = d[17], invL2_1 = d[18], invL2_2 = d[19];

            float dx = px - ax, dy = py - ay;
            float w1 = (dx * e1y - dy * e1x) * invden;
            float w2 = (e0x * dy - e0y * dx) * invden;
            float w0 = (1.0f - w1) - w2;
            bool inside = (w0 >= 0.0f) & (w1 >= 0.0f) & (w2 >= 0.0f);
            float zi = (w0 * z0 + w1 * z1) + w2 * z2;
            float score = inside ? zi : -1e10f;
            if (score > best) {
                best = score; bestf = (int)fidx; bw0 = w0; bw1 = w1; bw2 = w2;
            }

            // edge 0: a->b
            float t0 = fminf(fmaxf((dx * e0x + dy * e0y) * invL2_0, 0.0f), 1.0f);
            float x0 = dx - t0 * e0x, y0 = dy - t0 * e0y;
            float dd = x0 * x0 + y0 * y0;
            // edge 1: b->c
            float rx1 = px - bx, ry1 = py - by;
            float t1 = fminf(fmaxf((rx1 * e12x + ry1 * e12y) * invL2_1, 0.0f), 1.0f);
            float x1 = rx1 - t1 * e12x, y1 = ry1 - t1 * e12y;
            dd = fminf(dd, x1 * x1 + y1 * y1);
            // edge 2: c->a (edge vector = -e1, exact fp negation)
            float ex2 = -e1x, ey2 = -e1y;
            float rx2 = px - cx, ry2 = py - cy;
            float t2 = fminf(fmaxf((rx2 * ex2 + ry2 * ey2) * invL2_2, 0.0f), 1.0f);
            float x2 = rx2 - t2 * ex2, y2 = ry2 - t2 * ey2;
            dd = fminf(dd, x2 * x2 + y2 * y2);

            float d2 = inside ? 0.0f : dd;
            float prob = __expf(-7000.0f * d2);
            P *= (1.0f - prob);
        }
    }

    // cross-wave reduction (4 waves, same pixel = same lane)
    {
        float* my = &sred[tid * 7];
        my[0] = best; my[1] = __int_as_float(bestf);
        my[2] = bw0;  my[3] = bw1; my[4] = bw2; my[5] = P;
    }
    __syncthreads();

    if (tid < 64) {
        float bb = sred[tid * 7 + 0];
        int   bf = __float_as_int(sred[tid * 7 + 1]);
        float r0 = sred[tid * 7 + 2], r1 = sred[tid * 7 + 3], r2 = sred[tid * 7 + 4];
        float Pt = sred[tid * 7 + 5];
        for (int w = 1; w < NWAVES; ++w) {
            const float* s = &sred[(w * 64 + tid) * 7];
            float sc = s[0]; int ff = __float_as_int(s[1]);
            if ((sc > bb) || ((sc == bb) && (ff < bf))) {
                bb = sc; bf = ff; r0 = s[2]; r1 = s[3]; r2 = s[4];
            }
            Pt *= s[5];
        }

        bool hit = bb != -1e10f;
        float uv0 = 0.0f, uv1 = 0.0f;
        if (hit) {
            const float* fp = ffeat + bf * 6;
            uv0 = (fp[0] * r0 + fp[2] * r1) + fp[4] * r2;
            uv1 = (fp[1] * r0 + fp[3] * r1) + fp[5] * r2;
        }
        float u = fminf(fmaxf(uv0, 0.0f), 1.0f) * 255.0f;
        float v = (1.0f - fminf(fmaxf(uv1, 0.0f), 1.0f)) * 255.0f;
        float x0f = floorf(u), y0f = floorf(v);
        float fx = u - x0f, fy = v - y0f;
        int x0i = min(max((int)x0f, 0), 255);
        int x1i = min(x0i + 1, 255);
        int y0i = min(max((int)y0f, 0), 255);
        int y1i = min(y0i + 1, 255);

        for (int c = 0; c < 3; ++c) {
            const float* tc = tex + c * 65536;
            float t00 = tc[y0i * 256 + x0i];
            float t01 = tc[y0i * 256 + x1i];
            float t10 = tc[y1i * 256 + x0i];
            float t11 = tc[y1i * 256 + x1i];
            float val = (t00 * (1.0f - fx)) * (1.0f - fy);
            val = val + (t01 * fx) * (1.0f - fy);
            val = val + (t10 * (1.0f - fx)) * fy;
            val = val + (t11 * fx) * fy;
            out[((frame * 4 + c) * IMG_H + i) * IMG_W + j] = val;
        }
        maskbuf[(frame * IMG_H + i) * IMG_W + j] = 1.0f - Pt;
    }
}

// ---------- kernel 3: 5x5 erode (window min over valid region) ----------

__global__ void __launch_bounds__(256)
erode_kernel(const float* __restrict__ maskbuf, float* __restrict__ out)
{
    int frame = blockIdx.x >> 6;
    int pix = (blockIdx.x & 63) * 256 + threadIdx.x;
    int i = pix >> 7, j = pix & 127;
    float m = 1e30f;
    for (int di = -2; di <= 2; ++di) {
        int ii = i + di;
        if (ii < 0 || ii >= IMG_H) continue;
        for (int dj = -2; dj <= 2; ++dj) {
            int jj = j + dj;
            if (jj < 0 || jj >= IMG_W) continue;
            m = fminf(m, maskbuf[(frame * IMG_H + ii) * IMG_W + jj]);
        }
    }
    out[((frame * 4 + 3) * IMG_H + i) * IMG_W + j] = m;
}

// ---------- launcher ----------

extern "C" void kernel_launch(void* const* d_in, const int* in_sizes, int n_in,
                              void* d_out, int out_size, void* d_ws, size_t ws_size,
                              hipStream_t stream) {
    const float* vertices      = (const float*)d_in[0];
    const float* translation   = (const float*)d_in[1];
    const float* quaternion    = (const float*)d_in[2];
    const float* expv          = (const float*)d_in[3];
    const float* face_features = (const float*)d_in[4];
    const float* texture_maps  = (const float*)d_in[5];
    const int*   faces         = (const int*)d_in[6];
    float* out = (float*)d_out;

    int*   faceCount = (int*)d_ws;
    float* bbg       = (float*)d_ws + 4;                 // 4*4*320 floats
    float* recsg     = bbg + 4 * 4 * N_FACES;            // 4*320*20 floats (16B-aligned)
    float* maskbuf   = recsg + 4 * N_FACES * REC_SZ;     // 4*128*128 floats

    setup_kernel<<<1, 256, 0, stream>>>(vertices, translation, quaternion, expv,
                                        faces, faceCount, bbg, recsg);
    raster_kernel<<<N_FRAMES * 256, 256, 0, stream>>>(faceCount, bbg, recsg,
                                                      face_features, texture_maps,
                                                      out, maskbuf);
    erode_kernel<<<N_FRAMES * 64, 256, 0, stream>>>(maskbuf, out);
}

// Round 8
// 87.577 us; speedup vs baseline: 1.2295x; 1.0680x over previous
//
#include <hip/hip_runtime.h>
#include <math.h>

#define N_FRAMES 4
#define N_FACES  320
#define N_VERTS  162
#define IMG_H    128
#define IMG_W    128
#define NWAVES   8
#define FPW      40            // faces per wave (320/8), one ballot round
#define REC_SZ   20            // floats per compacted face record

// LDS arena, phase A (prologue + main loop):
//   sv   @ 0    : 162*3 floats = 1944 (pad 1952)
//   bb   @ 1952 : SoA [wave][4][48] = 6144
//   recs @ 8096 : [wave][FPW][REC_SZ] = 25600   -> total 33696
// phase B (after barrier, aliased over phase A):
//   red  @ 0    : 512*6 floats = 12288   (argmax + P partials)
#define SV_OFF   0
#define BB_OFF   1952
#define BB_LD    48
#define REC_OFF  8096
#define ARENA_SZ 33696

// Record (REC_SZ floats): ax,ay,e0x,e0y, e1x,e1y,invden,origidx,
//                         z0,z1,z2,invL2_0, bx,by,e12x,e12y, cx,cy,invL2_1,invL2_2

// ---------- small math helpers (fp32, op-order matched to the JAX reference) ----------

__device__ __forceinline__ void q_to_aa(const float* q, float* aa) {
    float q1 = q[1], q2 = q[2], q3 = q[3];
    float sin_sq = (q1 * q1 + q2 * q2) + q3 * q3;
    float sin_t = sqrtf(sin_sq + 1e-20f);
    float cos_t = q[0];
    float two_theta = (cos_t < 0.0f) ? (2.0f * atan2f(-sin_t, -cos_t))
                                     : (2.0f * atan2f(sin_t, cos_t));
    float k = (sin_sq > 1e-12f) ? (two_theta / sin_t) : 2.0f;
    aa[0] = q1 * k; aa[1] = q2 * k; aa[2] = q3 * k;
}

__device__ __forceinline__ void aa_to_R(const float* aa, float* R) {
    float th = sqrtf(((aa[0] * aa[0] + aa[1] * aa[1]) + aa[2] * aa[2]) + 1e-12f);
    float kx = aa[0] / th, ky = aa[1] / th, kz = aa[2] / th;
    float K[9] = { 0.0f, -kz,  ky,
                   kz,  0.0f, -kx,
                  -ky,   kx, 0.0f };
    float s = sinf(th), c = cosf(th);
    float KK[9];
    for (int i = 0; i < 3; ++i)
        for (int j = 0; j < 3; ++j)
            KK[i*3+j] = (K[i*3+0] * K[0*3+j] + K[i*3+1] * K[1*3+j]) + K[i*3+2] * K[2*3+j];
    float omc = 1.0f - c;
    for (int i = 0; i < 9; ++i) {
        float eye = (i == 0 || i == 4 || i == 8) ? 1.0f : 0.0f;
        R[i] = (eye + s * K[i]) + omc * KK[i];
    }
}

__device__ __forceinline__ void mat3mul(const float* A, const float* B, float* C) {
    for (int i = 0; i < 3; ++i)
        for (int j = 0; j < 3; ++j)
            C[i*3+j] = (A[i*3+0] * B[0*3+j] + A[i*3+1] * B[1*3+j]) + A[i*3+2] * B[2*3+j];
}

// ---------- fused kernel: per-block setup + rasterization + texture sample ----------
// Block = 512 threads = 8 waves, one 16x4 pixel tile (1 px/lane), one frame.
// Thread 0 computes the rotation chain ONCE per block (bit-identical to the
// per-wave version, minus 7 redundant instruction streams). Wave w owns faces
// [40w, 40w+40) (ballot-compacted). Cull vs the tile rect with margin
// 0.0026 > 25*ln2/7000 = 0.002476: skipped faces contribute a factor that
// rounds to exactly 1.0f at every tile pixel and cannot be inside -> bit-exact.

__global__ void __launch_bounds__(512)
render_kernel(const float* __restrict__ verts_in,   // 162*3
              const float* __restrict__ transl,     // 6 floats
              const float* __restrict__ quat,       // 8 floats
              const float* __restrict__ expv,       // 1 float
              const int*   __restrict__ faces,      // 320*3
              const float* __restrict__ ffeat,      // (320,3,2)
              const float* __restrict__ tex,        // (3,256,256)
              float* __restrict__ out,              // (4,4,128,128)
              float* __restrict__ maskbuf)          // (4,128,128)
{
    __shared__ __align__(16) char arena[ARENA_SZ];
    __shared__ float rotS[9];
    float* sv   = (float*)(arena + SV_OFF);
    float* bb   = (float*)(arena + BB_OFF);
    float* recs = (float*)(arena + REC_OFF);
    float* red  = (float*)arena;                    // aliased; used after barrier

    int frame = blockIdx.x >> 8;                    // 1024 blocks: 256 tiles/frame
    int blk   = blockIdx.x & 255;
    int tid   = threadIdx.x;
    int lane  = tid & 63;
    int wv    = __builtin_amdgcn_readfirstlane(tid >> 6);
    int tile_x = blk & 7, tile_y = blk >> 3;
    int j = tile_x * 16 + (lane & 15);
    int i = tile_y * 4 + (lane >> 4);

    float e = expv[0];

    // ---- prologue phase 1: rotation chain, thread 0 only -> LDS broadcast ----
    if (tid == 0) {
        float aa0[3], aa1[3], Rl[9], S[9];
        q_to_aa(quat, aa0);
        aa_to_R(aa0, Rl);
        q_to_aa(quat + 4, aa1);                     // angles (ROT_DIVIDE = 1)
        float arg[3];
        for (int t = 0; t < 3; ++t) arg[t] = (e * aa1[t]) / 4.0f;
        aa_to_R(arg, S);
        for (int t = 0; t < frame; ++t) {           // rot = rot @ rot_step, k times
            float nxt[9];
            mat3mul(Rl, S, nxt);
            for (int q = 0; q < 9; ++q) Rl[q] = nxt[q];
        }
        for (int q = 0; q < 9; ++q) rotS[q] = Rl[q];
    }
    __syncthreads();

    // ---- prologue phase 2: camera-space vertices for THIS frame ----
    if (tid < N_VERTS) {
        float te = (float)((double)frame / 3.0) * e;
        float vx = verts_in[tid*3+0], vy = verts_in[tid*3+1], vz = verts_in[tid*3+2];
        float dx_ = (rotS[0] * vx + rotS[1] * vy) + rotS[2] * vz;
        float dy_ = (rotS[3] * vx + rotS[4] * vy) + rotS[5] * vz;
        float dz_ = (rotS[6] * vx + rotS[7] * vy) + rotS[8] * vz;
        float x = (dx_ + transl[0]) + te * transl[3];
        float y = (dy_ + transl[1]) + te * transl[4];
        float z = (dz_ + transl[2]) + te * transl[5];
        z = z - 2.0f;                               // v_cam = verts - [0,0,CAM_DIST]
        sv[tid*3+0] = x; sv[tid*3+1] = y; sv[tid*3+2] = z;
    }
    __syncthreads();

    // ---- prologue phase 3: per-wave face setup + ballot compaction ----
    const float FOCAL = (float)(1.0 / tan(1.57 / 4.0));
    int cnt;
    {
        bool valid = false;
        float ax=0, ay=0, bx=0, by=0, cx=0, cy=0, e0x=0, e0y=0, e1x=0, e1y=0;
        float e12x=0, e12y=0, z0=0, z1=0, z2=0, den=0;
        int f = wv * FPW + lane;
        if (lane < FPW) {
            int i0 = faces[f*3+0], i1 = faces[f*3+1], i2 = faces[f*3+2];
            const float* A = &sv[i0*3];
            const float* B = &sv[i1*3];
            const float* C = &sv[i2*3];
            float ux = B[0] - A[0], uy = B[1] - A[1];
            float wx = C[0] - A[0], wy = C[1] - A[1];
            float nz = ux * wy - uy * wx;           // sign of face-normal z
            float da = -A[2] + 1e-10f, db = -B[2] + 1e-10f, dc = -C[2] + 1e-10f;
            ax = (FOCAL * A[0]) / da; ay = (FOCAL * A[1]) / da;
            bx = (FOCAL * B[0]) / db; by = (FOCAL * B[1]) / db;
            cx = (FOCAL * C[0]) / dc; cy = (FOCAL * C[1]) / dc;
            e0x = bx - ax; e0y = by - ay;
            e1x = cx - ax; e1y = cy - ay;
            e12x = cx - bx; e12y = cy - by;
            den = e0x * e1y - e0y * e1x;
            z0 = A[2]; z1 = B[2]; z2 = C[2];
            valid = (fabsf(den) > 1e-10f) && (nz > 0.0f);
        }
        unsigned long long m = __ballot(valid);
        cnt = __popcll(m);                          // wave-uniform
        if (valid) {
            unsigned long long lmask = (lane == 63) ? 0x7fffffffffffffffull
                                                    : ((1ull << lane) - 1ull);
            int pos = __popcll(m & lmask);
            float invden = 1.0f / den;
            float L2_0 = (e0x * e0x + e0y * e0y) + 1e-12f;
            float L2_1 = (e12x * e12x + e12y * e12y) + 1e-12f;
            float L2_2 = (e1x * e1x + e1y * e1y) + 1e-12f;   // |(-e1)|^2 == |e1|^2
            float4* r = (float4*)&recs[(wv * FPW + pos) * REC_SZ];
            r[0] = make_float4(ax, ay, e0x, e0y);
            r[1] = make_float4(e1x, e1y, invden, (float)f);
            r[2] = make_float4(z0, z1, z2, 1.0f / L2_0);
            r[3] = make_float4(bx, by, e12x, e12y);
            r[4] = make_float4(cx, cy, 1.0f / L2_1, 1.0f / L2_2);
            float* wbb = &bb[wv * 4 * BB_LD];
            wbb[0*BB_LD + pos] = fminf(fminf(ax, bx), cx);
            wbb[1*BB_LD + pos] = fminf(fminf(ay, by), cy);
            wbb[2*BB_LD + pos] = fmaxf(fmaxf(ax, bx), cx);
            wbb[3*BB_LD + pos] = fmaxf(fmaxf(ay, by), cy);
        }
    }
    // No barrier needed: each wave reads only its own compacted segment.

    // ---- per-pixel coordinates & wave tile rectangle ----
    float px = (float)(-1.0 + 2.0 * (double)j / 127.0);
    float py = (float)( 1.0 - 2.0 * (double)i / 127.0);
    float txmin = (float)(-1.0 + 2.0 * (double)(tile_x * 16) / 127.0);
    float txmax = (float)(-1.0 + 2.0 * (double)(tile_x * 16 + 15) / 127.0);
    float tymax = (float)( 1.0 - 2.0 * (double)(tile_y * 4) / 127.0);
    float tymin = (float)( 1.0 - 2.0 * (double)(tile_y * 4 + 3) / 127.0);

    // ---- cull pass: one vectorized bbox test per lane -> relevance bitmask ----
    unsigned long long fmask;
    {
        int l = (lane < FPW) ? lane : 0;
        const float* wbb = &bb[wv * 4 * BB_LD];
        float xmin = wbb[0*BB_LD + l], ymin = wbb[1*BB_LD + l];
        float xmax = wbb[2*BB_LD + l], ymax = wbb[3*BB_LD + l];
        float cdx = fmaxf(fmaxf(xmin - txmax, txmin - xmax), 0.0f);
        float cdy = fmaxf(fmaxf(ymin - tymax, tymin - ymax), 0.0f);
        bool near = ((cdx * cdx + cdy * cdy) <= 0.0026f) && (lane < cnt);
        fmask = __ballot(near);
    }

    // ---- main loop: only relevant faces ----
    float best = -1e10f;
    int bestf = 0;
    float bw0 = 0.0f, bw1 = 0.0f, bw2 = 0.0f;
    float P = 1.0f;

    while (fmask) {
        int fc = __ffsll((unsigned long long)fmask) - 1;   // wave-uniform
        fmask &= fmask - 1;
        const float* d = &recs[(wv * FPW + fc) * REC_SZ];  // uniform -> broadcast

        float ax = d[0], ay = d[1], e0x = d[2], e0y = d[3];
        float e1x = d[4], e1y = d[5], invden = d[6], fidx = d[7];
        float z0 = d[8], z1 = d[9], z2 = d[10], invL2_0 = d[11];
        float bx = d[12], by = d[13], e12x = d[14], e12y = d[15];
        float cx = d[16], cy = d[17], invL2_1 = d[18], invL2_2 = d[19];

        float dx = px - ax, dy = py - ay;
        float w1 = (dx * e1y - dy * e1x) * invden;
        float w2 = (e0x * dy - e0y * dx) * invden;
        float w0 = (1.0f - w1) - w2;
        bool inside = (w0 >= 0.0f) & (w1 >= 0.0f) & (w2 >= 0.0f);
        float zi = (w0 * z0 + w1 * z1) + w2 * z2;
        float score = inside ? zi : -1e10f;
        if (score > best) {
            best = score; bestf = (int)fidx; bw0 = w0; bw1 = w1; bw2 = w2;
        }

        // edge 0: a->b
        float t0 = fminf(fmaxf((dx * e0x + dy * e0y) * invL2_0, 0.0f), 1.0f);
        float x0 = dx - t0 * e0x, y0 = dy - t0 * e0y;
        float dd = x0 * x0 + y0 * y0;
        // edge 1: b->c
        float rx1 = px - bx, ry1 = py - by;
        float t1 = fminf(fmaxf((rx1 * e12x + ry1 * e12y) * invL2_1, 0.0f), 1.0f);
        float x1 = rx1 - t1 * e12x, y1 = ry1 - t1 * e12y;
        dd = fminf(dd, x1 * x1 + y1 * y1);
        // edge 2: c->a (edge vector = -e1, exact fp negation)
        float ex2 = -e1x, ey2 = -e1y;
        float rx2 = px - cx, ry2 = py - cy;
        float t2 = fminf(fmaxf((rx2 * ex2 + ry2 * ey2) * invL2_2, 0.0f), 1.0f);
        float x2 = rx2 - t2 * ex2, y2 = ry2 - t2 * ey2;
        dd = fminf(dd, x2 * x2 + y2 * y2);

        float d2 = inside ? 0.0f : dd;
        float prob = __expf(-7000.0f * d2);
        P *= (1.0f - prob);
    }

    // ---- cross-wave reduction (red aliases the arena: barrier both sides) ----
    __syncthreads();                               // all waves done with recs/bb
    float* my = &red[tid * 6];
    my[0] = best; my[1] = __int_as_float(bestf);
    my[2] = bw0;  my[3] = bw1; my[4] = bw2; my[5] = P;
    __syncthreads();

    if (tid < 64) {
        float bbst = red[tid * 6 + 0];
        int   bf   = __float_as_int(red[tid * 6 + 1]);
        float r0 = red[tid * 6 + 2], r1 = red[tid * 6 + 3], r2 = red[tid * 6 + 4];
        float Pt = red[tid * 6 + 5];
        for (int w = 1; w < NWAVES; ++w) {
            const float* s = &red[(w * 64 + tid) * 6];
            float sc = s[0]; int ff = __float_as_int(s[1]);
            if ((sc > bbst) || ((sc == bbst) && (ff < bf))) {
                bbst = sc; bf = ff; r0 = s[2]; r1 = s[3]; r2 = s[4];
            }
            Pt *= s[5];
        }

        bool hit = bbst != -1e10f;
        float uv0 = 0.0f, uv1 = 0.0f;
        if (hit) {
            const float* fp = ffeat + bf * 6;
            uv0 = (fp[0] * r0 + fp[2] * r1) + fp[4] * r2;
            uv1 = (fp[1] * r0 + fp[3] * r1) + fp[5] * r2;
        }
        float u = fminf(fmaxf(uv0, 0.0f), 1.0f) * 255.0f;
        float v = (1.0f - fminf(fmaxf(uv1, 0.0f), 1.0f)) * 255.0f;
        float x0f = floorf(u), y0f = floorf(v);
        float fx = u - x0f, fy = v - y0f;
        int x0i = min(max((int)x0f, 0), 255);
        int x1i = min(x0i + 1, 255);
        int y0i = min(max((int)y0f, 0), 255);
        int y1i = min(y0i + 1, 255);

        for (int c = 0; c < 3; ++c) {
            const float* tc = tex + c * 65536;
            float t00 = tc[y0i * 256 + x0i];
            float t01 = tc[y0i * 256 + x1i];
            float t10 = tc[y1i * 256 + x0i];
            float t11 = tc[y1i * 256 + x1i];
            float val = (t00 * (1.0f - fx)) * (1.0f - fy);
            val = val + (t01 * fx) * (1.0f - fy);
            val = val + (t10 * (1.0f - fx)) * fy;
            val = val + (t11 * fx) * fy;
            out[((frame * 4 + c) * IMG_H + i) * IMG_W + j] = val;
        }
        maskbuf[(frame * IMG_H + i) * IMG_W + j] = 1.0f - Pt;
    }
}

// ---------- kernel 2: 5x5 erode (window min over valid region) ----------

__global__ void __launch_bounds__(256)
erode_kernel(const float* __restrict__ maskbuf, float* __restrict__ out)
{
    int frame = blockIdx.x >> 6;
    int pix = (blockIdx.x & 63) * 256 + threadIdx.x;
    int i = pix >> 7, j = pix & 127;
    float m = 1e30f;
    for (int di = -2; di <= 2; ++di) {
        int ii = i + di;
        if (ii < 0 || ii >= IMG_H) continue;
        for (int dj = -2; dj <= 2; ++dj) {
            int jj = j + dj;
            if (jj < 0 || jj >= IMG_W) continue;
            m = fminf(m, maskbuf[(frame * IMG_H + ii) * IMG_W + jj]);
        }
    }
    out[((frame * 4 + 3) * IMG_H + i) * IMG_W + j] = m;
}

// ---------- launcher ----------

extern "C" void kernel_launch(void* const* d_in, const int* in_sizes, int n_in,
                              void* d_out, int out_size, void* d_ws, size_t ws_size,
                              hipStream_t stream) {
    const float* vertices      = (const float*)d_in[0];
    const float* translation   = (const float*)d_in[1];
    const float* quaternion    = (const float*)d_in[2];
    const float* expv          = (const float*)d_in[3];
    const float* face_features = (const float*)d_in[4];
    const float* texture_maps  = (const float*)d_in[5];
    const int*   faces         = (const int*)d_in[6];
    float* out = (float*)d_out;

    float* maskbuf = (float*)d_ws;                 // 4*128*128 floats

    render_kernel<<<N_FRAMES * 256, 512, 0, stream>>>(vertices, translation,
                                                      quaternion, expv, faces,
                                                      face_features, texture_maps,
                                                      out, maskbuf);
    erode_kernel<<<N_FRAMES * 64, 256, 0, stream>>>(maskbuf, out);
}

// Round 9
// 86.588 us; speedup vs baseline: 1.2435x; 1.0114x over previous
//
#include <hip/hip_runtime.h>
#include <math.h>

#define N_FRAMES 4
#define N_FACES  320
#define N_VERTS  162
#define IMG_H    128
#define IMG_W    128
#define NWAVES   8
#define FPW      40            // faces per wave (320/8), one ballot round
#define REC_SZ   20            // floats per compacted face record

// LDS arena, phase A (prologue + main loop):
//   sv   @ 0    : 162*3 floats = 1944 (pad 1952)
//   bb   @ 1952 : SoA [wave][4][48] = 6144
//   recs @ 8096 : [wave][FPW][REC_SZ] = 25600   -> total 33696
// phase B (after barrier, aliased over phase A):
//   red  @ 0    : 512*6 floats = 12288   (argmax + P partials)
#define SV_OFF   0
#define BB_OFF   1952
#define BB_LD    48
#define REC_OFF  8096
#define ARENA_SZ 33696

// Record (REC_SZ floats): ax,ay,e0x,e0y, e1x,e1y,invden,origidx,
//                         z0,z1,z2,invL2_0, bx,by,e12x,e12y, cx,cy,invL2_1,invL2_2

// ---------- small math helpers (fp32, op-order matched to the JAX reference) ----------

__device__ __forceinline__ void q_to_aa(const float* q, float* aa) {
    float q1 = q[1], q2 = q[2], q3 = q[3];
    float sin_sq = (q1 * q1 + q2 * q2) + q3 * q3;
    float sin_t = sqrtf(sin_sq + 1e-20f);
    float cos_t = q[0];
    float two_theta = (cos_t < 0.0f) ? (2.0f * atan2f(-sin_t, -cos_t))
                                     : (2.0f * atan2f(sin_t, cos_t));
    float k = (sin_sq > 1e-12f) ? (two_theta / sin_t) : 2.0f;
    aa[0] = q1 * k; aa[1] = q2 * k; aa[2] = q3 * k;
}

__device__ __forceinline__ void aa_to_R(const float* aa, float* R) {
    float th = sqrtf(((aa[0] * aa[0] + aa[1] * aa[1]) + aa[2] * aa[2]) + 1e-12f);
    float kx = aa[0] / th, ky = aa[1] / th, kz = aa[2] / th;
    float K[9] = { 0.0f, -kz,  ky,
                   kz,  0.0f, -kx,
                  -ky,   kx, 0.0f };
    float s = sinf(th), c = cosf(th);
    float KK[9];
    for (int i = 0; i < 3; ++i)
        for (int j = 0; j < 3; ++j)
            KK[i*3+j] = (K[i*3+0] * K[0*3+j] + K[i*3+1] * K[1*3+j]) + K[i*3+2] * K[2*3+j];
    float omc = 1.0f - c;
    for (int i = 0; i < 9; ++i) {
        float eye = (i == 0 || i == 4 || i == 8) ? 1.0f : 0.0f;
        R[i] = (eye + s * K[i]) + omc * KK[i];
    }
}

__device__ __forceinline__ void mat3mul(const float* A, const float* B, float* C) {
    for (int i = 0; i < 3; ++i)
        for (int j = 0; j < 3; ++j)
            C[i*3+j] = (A[i*3+0] * B[0*3+j] + A[i*3+1] * B[1*3+j]) + A[i*3+2] * B[2*3+j];
}

// ---------- fused kernel: per-block setup + rasterization + texture sample ----------
// Block = 512 threads = 8 waves, one 16x4 pixel tile (1 px/lane), one frame.
// Thread 0 computes the rotation chain once per block. Wave w owns faces
// [40w, 40w+40) (ballot-compacted). Cull vs the tile rect with margin
// 0.0026 > 25*ln2/7000 = 0.002476: skipped faces contribute a factor that
// rounds to exactly 1.0f at every tile pixel and cannot be inside -> bit-exact.
// P-dead-path skip: once ALL lanes have P == 0.0f exactly (pixel inside some
// face => factor exactly 0, and 0 * finite == 0 forever), the edge-distance/
// exp/product half of the body is provably dead and skipped -> bit-exact.

__global__ void __launch_bounds__(512)
render_kernel(const float* __restrict__ verts_in,   // 162*3
              const float* __restrict__ transl,     // 6 floats
              const float* __restrict__ quat,       // 8 floats
              const float* __restrict__ expv,       // 1 float
              const int*   __restrict__ faces,      // 320*3
              const float* __restrict__ ffeat,      // (320,3,2)
              const float* __restrict__ tex,        // (3,256,256)
              float* __restrict__ out,              // (4,4,128,128)
              float* __restrict__ maskbuf)          // (4,128,128)
{
    __shared__ __align__(16) char arena[ARENA_SZ];
    __shared__ float rotS[9];
    float* sv   = (float*)(arena + SV_OFF);
    float* bb   = (float*)(arena + BB_OFF);
    float* recs = (float*)(arena + REC_OFF);
    float* red  = (float*)arena;                    // aliased; used after barrier

    int frame = blockIdx.x >> 8;                    // 1024 blocks: 256 tiles/frame
    int blk   = blockIdx.x & 255;
    int tid   = threadIdx.x;
    int lane  = tid & 63;
    int wv    = __builtin_amdgcn_readfirstlane(tid >> 6);
    int tile_x = blk & 7, tile_y = blk >> 3;
    int j = tile_x * 16 + (lane & 15);
    int i = tile_y * 4 + (lane >> 4);

    float e = expv[0];

    // ---- prologue phase 1: rotation chain, thread 0 only -> LDS broadcast ----
    if (tid == 0) {
        float aa0[3], aa1[3], Rl[9], S[9];
        q_to_aa(quat, aa0);
        aa_to_R(aa0, Rl);
        q_to_aa(quat + 4, aa1);                     // angles (ROT_DIVIDE = 1)
        float arg[3];
        for (int t = 0; t < 3; ++t) arg[t] = (e * aa1[t]) / 4.0f;
        aa_to_R(arg, S);
        for (int t = 0; t < frame; ++t) {           // rot = rot @ rot_step, k times
            float nxt[9];
            mat3mul(Rl, S, nxt);
            for (int q = 0; q < 9; ++q) Rl[q] = nxt[q];
        }
        for (int q = 0; q < 9; ++q) rotS[q] = Rl[q];
    }
    __syncthreads();

    // ---- prologue phase 2: camera-space vertices for THIS frame ----
    if (tid < N_VERTS) {
        float te = (float)((double)frame / 3.0) * e;
        float vx = verts_in[tid*3+0], vy = verts_in[tid*3+1], vz = verts_in[tid*3+2];
        float dx_ = (rotS[0] * vx + rotS[1] * vy) + rotS[2] * vz;
        float dy_ = (rotS[3] * vx + rotS[4] * vy) + rotS[5] * vz;
        float dz_ = (rotS[6] * vx + rotS[7] * vy) + rotS[8] * vz;
        float x = (dx_ + transl[0]) + te * transl[3];
        float y = (dy_ + transl[1]) + te * transl[4];
        float z = (dz_ + transl[2]) + te * transl[5];
        z = z - 2.0f;                               // v_cam = verts - [0,0,CAM_DIST]
        sv[tid*3+0] = x; sv[tid*3+1] = y; sv[tid*3+2] = z;
    }
    __syncthreads();

    // ---- prologue phase 3: per-wave face setup + ballot compaction ----
    const float FOCAL = (float)(1.0 / tan(1.57 / 4.0));
    int cnt;
    {
        bool valid = false;
        float ax=0, ay=0, bx=0, by=0, cx=0, cy=0, e0x=0, e0y=0, e1x=0, e1y=0;
        float e12x=0, e12y=0, z0=0, z1=0, z2=0, den=0;
        int f = wv * FPW + lane;
        if (lane < FPW) {
            int i0 = faces[f*3+0], i1 = faces[f*3+1], i2 = faces[f*3+2];
            const float* A = &sv[i0*3];
            const float* B = &sv[i1*3];
            const float* C = &sv[i2*3];
            float ux = B[0] - A[0], uy = B[1] - A[1];
            float wx = C[0] - A[0], wy = C[1] - A[1];
            float nz = ux * wy - uy * wx;           // sign of face-normal z
            float da = -A[2] + 1e-10f, db = -B[2] + 1e-10f, dc = -C[2] + 1e-10f;
            ax = (FOCAL * A[0]) / da; ay = (FOCAL * A[1]) / da;
            bx = (FOCAL * B[0]) / db; by = (FOCAL * B[1]) / db;
            cx = (FOCAL * C[0]) / dc; cy = (FOCAL * C[1]) / dc;
            e0x = bx - ax; e0y = by - ay;
            e1x = cx - ax; e1y = cy - ay;
            e12x = cx - bx; e12y = cy - by;
            den = e0x * e1y - e0y * e1x;
            z0 = A[2]; z1 = B[2]; z2 = C[2];
            valid = (fabsf(den) > 1e-10f) && (nz > 0.0f);
        }
        unsigned long long m = __ballot(valid);
        cnt = __popcll(m);                          // wave-uniform
        if (valid) {
            unsigned long long lmask = (lane == 63) ? 0x7fffffffffffffffull
                                                    : ((1ull << lane) - 1ull);
            int pos = __popcll(m & lmask);
            float invden = 1.0f / den;
            float L2_0 = (e0x * e0x + e0y * e0y) + 1e-12f;
            float L2_1 = (e12x * e12x + e12y * e12y) + 1e-12f;
            float L2_2 = (e1x * e1x + e1y * e1y) + 1e-12f;   // |(-e1)|^2 == |e1|^2
            float4* r = (float4*)&recs[(wv * FPW + pos) * REC_SZ];
            r[0] = make_float4(ax, ay, e0x, e0y);
            r[1] = make_float4(e1x, e1y, invden, (float)f);
            r[2] = make_float4(z0, z1, z2, 1.0f / L2_0);
            r[3] = make_float4(bx, by, e12x, e12y);
            r[4] = make_float4(cx, cy, 1.0f / L2_1, 1.0f / L2_2);
            float* wbb = &bb[wv * 4 * BB_LD];
            wbb[0*BB_LD + pos] = fminf(fminf(ax, bx), cx);
            wbb[1*BB_LD + pos] = fminf(fminf(ay, by), cy);
            wbb[2*BB_LD + pos] = fmaxf(fmaxf(ax, bx), cx);
            wbb[3*BB_LD + pos] = fmaxf(fmaxf(ay, by), cy);
        }
    }
    // No barrier needed: each wave reads only its own compacted segment.

    // ---- per-pixel coordinates & wave tile rectangle ----
    float px = (float)(-1.0 + 2.0 * (double)j / 127.0);
    float py = (float)( 1.0 - 2.0 * (double)i / 127.0);
    float txmin = (float)(-1.0 + 2.0 * (double)(tile_x * 16) / 127.0);
    float txmax = (float)(-1.0 + 2.0 * (double)(tile_x * 16 + 15) / 127.0);
    float tymax = (float)( 1.0 - 2.0 * (double)(tile_y * 4) / 127.0);
    float tymin = (float)( 1.0 - 2.0 * (double)(tile_y * 4 + 3) / 127.0);

    // ---- cull pass: one vectorized bbox test per lane -> relevance bitmask ----
    unsigned long long fmask;
    {
        int l = (lane < FPW) ? lane : 0;
        const float* wbb = &bb[wv * 4 * BB_LD];
        float xmin = wbb[0*BB_LD + l], ymin = wbb[1*BB_LD + l];
        float xmax = wbb[2*BB_LD + l], ymax = wbb[3*BB_LD + l];
        float cdx = fmaxf(fmaxf(xmin - txmax, txmin - xmax), 0.0f);
        float cdy = fmaxf(fmaxf(ymin - tymax, tymin - ymax), 0.0f);
        bool near = ((cdx * cdx + cdy * cdy) <= 0.0026f) && (lane < cnt);
        fmask = __ballot(near);
    }

    // ---- main loop: only relevant faces; P-dead-path skip once all lanes P==0 ----
    float best = -1e10f;
    int bestf = 0;
    float bw0 = 0.0f, bw1 = 0.0f, bw2 = 0.0f;
    float P = 1.0f;
    bool pzero = false;                            // wave-uniform: all lanes P==0

    while (fmask) {
        int fc = __ffsll((unsigned long long)fmask) - 1;   // wave-uniform
        fmask &= fmask - 1;
        const float* d = &recs[(wv * FPW + fc) * REC_SZ];  // uniform -> broadcast

        float ax = d[0], ay = d[1], e0x = d[2], e0y = d[3];
        float e1x = d[4], e1y = d[5], invden = d[6], fidx = d[7];
        float z0 = d[8], z1 = d[9], z2 = d[10];

        float dx = px - ax, dy = py - ay;
        float w1 = (dx * e1y - dy * e1x) * invden;
        float w2 = (e0x * dy - e0y * dx) * invden;
        float w0 = (1.0f - w1) - w2;
        bool inside = (w0 >= 0.0f) & (w1 >= 0.0f) & (w2 >= 0.0f);
        float zi = (w0 * z0 + w1 * z1) + w2 * z2;
        float score = inside ? zi : -1e10f;
        if (score > best) {
            best = score; bestf = (int)fidx; bw0 = w0; bw1 = w1; bw2 = w2;
        }

        if (!pzero) {                              // wave-uniform branch
            float invL2_0 = d[11];
            float bx = d[12], by = d[13], e12x = d[14], e12y = d[15];
            float cx = d[16], cy = d[17], invL2_1 = d[18], invL2_2 = d[19];
            // edge 0: a->b
            float t0 = fminf(fmaxf((dx * e0x + dy * e0y) * invL2_0, 0.0f), 1.0f);
            float x0 = dx - t0 * e0x, y0 = dy - t0 * e0y;
            float dd = x0 * x0 + y0 * y0;
            // edge 1: b->c
            float rx1 = px - bx, ry1 = py - by;
            float t1 = fminf(fmaxf((rx1 * e12x + ry1 * e12y) * invL2_1, 0.0f), 1.0f);
            float x1 = rx1 - t1 * e12x, y1 = ry1 - t1 * e12y;
            dd = fminf(dd, x1 * x1 + y1 * y1);
            // edge 2: c->a (edge vector = -e1, exact fp negation)
            float ex2 = -e1x, ey2 = -e1y;
            float rx2 = px - cx, ry2 = py - cy;
            float t2 = fminf(fmaxf((rx2 * ex2 + ry2 * ey2) * invL2_2, 0.0f), 1.0f);
            float x2 = rx2 - t2 * ex2, y2 = ry2 - t2 * ey2;
            dd = fminf(dd, x2 * x2 + y2 * y2);

            float d2 = inside ? 0.0f : dd;
            float prob = __expf(-7000.0f * d2);
            P *= (1.0f - prob);
            pzero = __all(P == 0.0f);
        }
    }

    // ---- cross-wave reduction (red aliases the arena: barrier both sides) ----
    __syncthreads();                               // all waves done with recs/bb
    float* my = &red[tid * 6];
    my[0] = best; my[1] = __int_as_float(bestf);
    my[2] = bw0;  my[3] = bw1; my[4] = bw2; my[5] = P;
    __syncthreads();

    if (tid < 64) {
        float bbst = red[tid * 6 + 0];
        int   bf   = __float_as_int(red[tid * 6 + 1]);
        float r0 = red[tid * 6 + 2], r1 = red[tid * 6 + 3], r2 = red[tid * 6 + 4];
        float Pt = red[tid * 6 + 5];
        for (int w = 1; w < NWAVES; ++w) {
            const float* s = &red[(w * 64 + tid) * 6];
            float sc = s[0]; int ff = __float_as_int(s[1]);
            if ((sc > bbst) || ((sc == bbst) && (ff < bf))) {
                bbst = sc; bf = ff; r0 = s[2]; r1 = s[3]; r2 = s[4];
            }
            Pt *= s[5];
        }

        bool hit = bbst != -1e10f;
        float uv0 = 0.0f, uv1 = 0.0f;
        if (hit) {
            const float* fp = ffeat + bf * 6;
            uv0 = (fp[0] * r0 + fp[2] * r1) + fp[4] * r2;
            uv1 = (fp[1] * r0 + fp[3] * r1) + fp[5] * r2;
        }
        float u = fminf(fmaxf(uv0, 0.0f), 1.0f) * 255.0f;
        float v = (1.0f - fminf(fmaxf(uv1, 0.0f), 1.0f)) * 255.0f;
        float x0f = floorf(u), y0f = floorf(v);
        float fx = u - x0f, fy = v - y0f;
        int x0i = min(max((int)x0f, 0), 255);
        int x1i = min(x0i + 1, 255);
        int y0i = min(max((int)y0f, 0), 255);
        int y1i = min(y0i + 1, 255);

        for (int c = 0; c < 3; ++c) {
            const float* tc = tex + c * 65536;
            float t00 = tc[y0i * 256 + x0i];
            float t01 = tc[y0i * 256 + x1i];
            float t10 = tc[y1i * 256 + x0i];
            float t11 = tc[y1i * 256 + x1i];
            float val = (t00 * (1.0f - fx)) * (1.0f - fy);
            val = val + (t01 * fx) * (1.0f - fy);
            val = val + (t10 * (1.0f - fx)) * fy;
            val = val + (t11 * fx) * fy;
            out[((frame * 4 + c) * IMG_H + i) * IMG_W + j] = val;
        }
        maskbuf[(frame * IMG_H + i) * IMG_W + j] = 1.0f - Pt;
    }
}

// ---------- kernel 2: 5x5 erode (window min over valid region) ----------

__global__ void __launch_bounds__(256)
erode_kernel(const float* __restrict__ maskbuf, float* __restrict__ out)
{
    int frame = blockIdx.x >> 6;
    int pix = (blockIdx.x & 63) * 256 + threadIdx.x;
    int i = pix >> 7, j = pix & 127;
    float m = 1e30f;
    for (int di = -2; di <= 2; ++di) {
        int ii = i + di;
        if (ii < 0 || ii >= IMG_H) continue;
        for (int dj = -2; dj <= 2; ++dj) {
            int jj = j + dj;
            if (jj < 0 || jj >= IMG_W) continue;
            m = fminf(m, maskbuf[(frame * IMG_H + ii) * IMG_W + jj]);
        }
    }
    out[((frame * 4 + 3) * IMG_H + i) * IMG_W + j] = m;
}

// ---------- launcher ----------

extern "C" void kernel_launch(void* const* d_in, const int* in_sizes, int n_in,
                              void* d_out, int out_size, void* d_ws, size_t ws_size,
                              hipStream_t stream) {
    const float* vertices      = (const float*)d_in[0];
    const float* translation   = (const float*)d_in[1];
    const float* quaternion    = (const float*)d_in[2];
    const float* expv          = (const float*)d_in[3];
    const float* face_features = (const float*)d_in[4];
    const float* texture_maps  = (const float*)d_in[5];
    const int*   faces         = (const int*)d_in[6];
    float* out = (float*)d_out;

    float* maskbuf = (float*)d_ws;                 // 4*128*128 floats

    render_kernel<<<N_FRAMES * 256, 512, 0, stream>>>(vertices, translation,
                                                      quaternion, expv, faces,
                                                      face_features, texture_maps,
                                                      out, maskbuf);
    erode_kernel<<<N_FRAMES * 64, 256, 0, stream>>>(maskbuf, out);
}